// Round 1
// baseline (172.807 us; speedup 1.0000x reference)
//
#include <hip/hip_runtime.h>
#include <hip/hip_bf16.h>

#define NN 32
#define LL 4096
#define EE 512
#define HH 8
#define DD 64
#define FF 2048
#define CC 8            // row chunks per head-block (512 rows / 64)

// ---------------------------------------------------------------------------
// K1: partial row-block sums of Cp.
// P[c][n][h][e] = sum over 64 rows (l = h*512 + c*64 .. +63) of Cp[n][l][e]
// grid = N*H*CC = 2048 blocks, 128 threads (one float4 column each)
__global__ void k_rowsum(const float* __restrict__ Cp, float* __restrict__ P) {
    int bid = blockIdx.x;              // n*64 + h*8 + c
    int c = bid & 7;
    int h = (bid >> 3) & 7;
    int n = bid >> 6;
    int e4 = threadIdx.x;              // 0..127
    const float4* base = reinterpret_cast<const float4*>(
        Cp + ((size_t)n * LL + (size_t)h * 512 + (size_t)c * 64) * EE) + e4;
    float ax = 0.f, ay = 0.f, az = 0.f, aw = 0.f;
#pragma unroll 8
    for (int r = 0; r < 64; ++r) {
        float4 v = base[(size_t)r * (EE / 4)];
        ax += v.x; ay += v.y; az += v.z; aw += v.w;
    }
    float4 o; o.x = ax; o.y = ay; o.z = az; o.w = aw;
    reinterpret_cast<float4*>(P + (((size_t)c * NN + n) * HH + h) * EE)[e4] = o;
}

// ---------------------------------------------------------------------------
// K2: V[d][e] = sum_{j<8} W1[j*64+d][e]    (column sums of W1 across heads)
// grid = 32 blocks x 256 threads -> 8192 float4 outputs
__global__ void k_colsum(const float* __restrict__ W1, float* __restrict__ V) {
    int gid = blockIdx.x * blockDim.x + threadIdx.x;   // 0..8191
    int d = gid >> 7;
    int e4 = gid & 127;
    float ax = 0.f, ay = 0.f, az = 0.f, aw = 0.f;
#pragma unroll
    for (int j = 0; j < 8; ++j) {
        float4 v = reinterpret_cast<const float4*>(W1 + (size_t)(j * 64 + d) * EE)[e4];
        ax += v.x; ay += v.y; az += v.z; aw += v.w;
    }
    float4 o; o.x = ax; o.y = ay; o.z = az; o.w = aw;
    reinterpret_cast<float4*>(V + (size_t)d * EE)[e4] = o;
}

// ---------------------------------------------------------------------------
// K3: combine partials into S[n,h,:] (LDS) and compute phi[n, h*64+d] = S·V[d]
// grid = N*H = 256 blocks x 256 threads
__global__ void k_phi(const float* __restrict__ P, const float* __restrict__ V,
                      float* __restrict__ phi) {
    __shared__ float S[EE];
    __shared__ float red[256];
    int n = blockIdx.x >> 3;
    int h = blockIdx.x & 7;
    for (int e = threadIdx.x; e < EE; e += 256) {
        float s = 0.f;
#pragma unroll
        for (int c = 0; c < CC; ++c)
            s += P[(((size_t)c * NN + n) * HH + h) * EE + e];
        S[e] = s;
    }
    __syncthreads();
    int d  = threadIdx.x >> 2;    // 0..63
    int ch = threadIdx.x & 3;     // 0..3 (each covers 128 e)
    const float* Vr = V + (size_t)d * EE + ch * 128;
    const float* Sr = S + ch * 128;
    float acc = 0.f;
#pragma unroll 4
    for (int e = 0; e < 128; ++e) acc += Sr[e] * Vr[e];
    red[threadIdx.x] = acc;
    __syncthreads();
    if (threadIdx.x < DD) {
        int dd = threadIdx.x;
        float r = red[dd * 4] + red[dd * 4 + 1] + red[dd * 4 + 2] + red[dd * 4 + 3];
        phi[(size_t)n * EE + h * DD + dd] = r;
    }
}

// ---------------------------------------------------------------------------
// K4: w3[n][f] = sum_e phi[n][e] * W3[f][e]   (64 blocks x 256)
__global__ void k_w3(const float* __restrict__ phi, const float* __restrict__ W3,
                     float* __restrict__ w3) {
    int gid = blockIdx.x * 256 + threadIdx.x;   // 0..16383
    int f = gid & (EE - 1);
    int n = gid >> 9;
    const float4* pr = reinterpret_cast<const float4*>(phi + (size_t)n * EE);
    const float4* wr = reinterpret_cast<const float4*>(W3 + (size_t)f * EE);
    float acc = 0.f;
#pragma unroll 4
    for (int e = 0; e < EE / 4; ++e) {
        float4 p = pr[e], w = wr[e];
        acc += p.x * w.x + p.y * w.y + p.z * w.z + p.w * w.w;
    }
    w3[gid] = acc;
}

// ---------------------------------------------------------------------------
// K5: h1[n][f] = relu(sum_e w3[n][e] * Wf1[f][e] + bf1[f])   (256 blocks x 256)
__global__ void k_ffn1(const float* __restrict__ w3, const float* __restrict__ Wf1,
                       const float* __restrict__ bf1, float* __restrict__ h1) {
    int gid = blockIdx.x * 256 + threadIdx.x;   // 0..65535
    int f = gid & (FF - 1);
    int n = gid >> 11;
    const float4* xr = reinterpret_cast<const float4*>(w3 + (size_t)n * EE);
    const float4* wr = reinterpret_cast<const float4*>(Wf1 + (size_t)f * EE);
    float acc = bf1[f];
#pragma unroll 4
    for (int e = 0; e < EE / 4; ++e) {
        float4 p = xr[e], w = wr[e];
        acc += p.x * w.x + p.y * w.y + p.z * w.z + p.w * w.w;
    }
    h1[gid] = fmaxf(acc, 0.f);
}

// ---------------------------------------------------------------------------
// K6: x[n][e] = w3[n][e] + sum_f h1[n][f] * Wf2[e][f] + bf2[e]   (64 blocks x 256)
__global__ void k_ffn2(const float* __restrict__ h1, const float* __restrict__ Wf2,
                       const float* __restrict__ bf2, const float* __restrict__ w3,
                       float* __restrict__ x) {
    int gid = blockIdx.x * 256 + threadIdx.x;   // 0..16383
    int e = gid & (EE - 1);
    int n = gid >> 9;
    const float4* hr = reinterpret_cast<const float4*>(h1 + (size_t)n * FF);
    const float4* wr = reinterpret_cast<const float4*>(Wf2 + (size_t)e * FF);
    float acc = bf2[e];
#pragma unroll 4
    for (int fo = 0; fo < FF / 4; ++fo) {
        float4 p = hr[fo], w = wr[fo];
        acc += p.x * w.x + p.y * w.y + p.z * w.z + p.w * w.w;
    }
    x[gid] = acc + w3[gid];
}

// ---------------------------------------------------------------------------
// K7: LayerNorm rows of x -> out.  32 blocks x 256 threads (2 elems/thread)
__global__ void k_ln(const float* __restrict__ x, const float* __restrict__ gamma,
                     const float* __restrict__ beta, float* __restrict__ out) {
    __shared__ float wred[4];
    int n = blockIdx.x;
    int tid = threadIdx.x;
    float a = x[(size_t)n * EE + tid];
    float b = x[(size_t)n * EE + 256 + tid];
    float s = a + b;
#pragma unroll
    for (int off = 32; off > 0; off >>= 1) s += __shfl_down(s, off);
    int wid = tid >> 6;
    if ((tid & 63) == 0) wred[wid] = s;
    __syncthreads();
    if (tid == 0) wred[0] = (wred[0] + wred[1] + wred[2] + wred[3]) * (1.0f / EE);
    __syncthreads();
    float mu = wred[0];
    float da = a - mu, db = b - mu;
    float q = da * da + db * db;
#pragma unroll
    for (int off = 32; off > 0; off >>= 1) q += __shfl_down(q, off);
    __syncthreads();                       // everyone has read mu
    if ((tid & 63) == 0) wred[wid] = q;
    __syncthreads();
    if (tid == 0) wred[0] = (wred[0] + wred[1] + wred[2] + wred[3]) * (1.0f / EE);
    __syncthreads();
    float var = wred[0];
    float rstd = rsqrtf(var + 1e-5f);
    out[(size_t)n * EE + tid]       = da * rstd * gamma[tid] + beta[tid];
    out[(size_t)n * EE + 256 + tid] = db * rstd * gamma[tid + 256] + beta[tid + 256];
}

// ---------------------------------------------------------------------------
extern "C" void kernel_launch(void* const* d_in, const int* in_sizes, int n_in,
                              void* d_out, int out_size, void* d_ws, size_t ws_size,
                              hipStream_t stream) {
    const float* Cp    = (const float*)d_in[0];
    const float* W1    = (const float*)d_in[1];
    // d_in[2] = W2: unused — softmax over a size-1 axis is identically 1.
    const float* W3    = (const float*)d_in[3];
    const float* Wf1   = (const float*)d_in[4];
    const float* bf1   = (const float*)d_in[5];
    const float* Wf2   = (const float*)d_in[6];
    const float* bf2   = (const float*)d_in[7];
    const float* gamma = (const float*)d_in[8];
    const float* beta  = (const float*)d_in[9];
    float* out = (float*)d_out;

    float* ws  = (float*)d_ws;
    float* P   = ws;                        // CC*NN*HH*EE = 1,048,576 floats (4 MB)
    float* V   = P + (size_t)CC * NN * HH * EE;   // 64*512 = 32768
    float* phi = V + (size_t)DD * EE;             // 32*512 = 16384
    float* w3  = phi + (size_t)NN * EE;           // 16384
    float* h1  = w3 + (size_t)NN * EE;            // 32*2048 = 65536
    float* x   = h1 + (size_t)NN * FF;            // 16384

    k_rowsum<<<NN * HH * CC, 128, 0, stream>>>(Cp, P);
    k_colsum<<<32, 256, 0, stream>>>(W1, V);
    k_phi   <<<NN * HH, 256, 0, stream>>>(P, V, phi);
    k_w3    <<<(NN * EE) / 256, 256, 0, stream>>>(phi, W3, w3);
    k_ffn1  <<<(NN * FF) / 256, 256, 0, stream>>>(w3, Wf1, bf1, h1);
    k_ffn2  <<<(NN * EE) / 256, 256, 0, stream>>>(h1, Wf2, bf2, w3, x);
    k_ln    <<<NN, 256, 0, stream>>>(x, gamma, beta, out);
}

// Round 2
// 77.411 us; speedup vs baseline: 2.2323x; 2.2323x over previous
//
#include <hip/hip_runtime.h>
#include <hip/hip_bf16.h>

#define NN 32
#define LL 4096
#define EE 512
#define HH 8
#define DD 64
#define FF 2048
#define CC 8            // row chunks per head-block (512 rows / 64)

// ---------------------------------------------------------------------------
// K1: fused (a) partial row-block sums of Cp and (b) column sums of W1.
// blocks 0..2047: P[c][n][h][e] = sum over 64 rows of Cp[n][h*512+c*64 + r][e]
// blocks 2048..2079: V[d][e] = sum_{j<8} W1[j*64+d][e]
__global__ void k_prep(const float* __restrict__ Cp, const float* __restrict__ W1,
                       float* __restrict__ P, float* __restrict__ V) {
    int bid = blockIdx.x;
    int tid = threadIdx.x;                 // 0..127
    if (bid < 2048) {
        int c = bid & 7;
        int h = (bid >> 3) & 7;
        int n = bid >> 6;
        const float4* base = reinterpret_cast<const float4*>(
            Cp + ((size_t)n * LL + (size_t)h * 512 + (size_t)c * 64) * EE) + tid;
        float ax = 0.f, ay = 0.f, az = 0.f, aw = 0.f;
#pragma unroll 8
        for (int r = 0; r < 64; ++r) {
            float4 v = base[(size_t)r * (EE / 4)];
            ax += v.x; ay += v.y; az += v.z; aw += v.w;
        }
        float4 o; o.x = ax; o.y = ay; o.z = az; o.w = aw;
        reinterpret_cast<float4*>(P + (((size_t)c * NN + n) * HH + h) * EE)[tid] = o;
    } else {
        int gid2 = (bid - 2048) * 128 + tid;     // 0..4095, 2 float4 outputs each
#pragma unroll
        for (int rep = 0; rep < 2; ++rep) {
            int idx = gid2 + rep * 4096;         // 0..8191
            int d = idx >> 7;
            int e4 = idx & 127;
            float ax = 0.f, ay = 0.f, az = 0.f, aw = 0.f;
#pragma unroll
            for (int j = 0; j < 8; ++j) {
                float4 v = reinterpret_cast<const float4*>(
                    W1 + (size_t)(j * 64 + d) * EE)[e4];
                ax += v.x; ay += v.y; az += v.z; aw += v.w;
            }
            float4 o; o.x = ax; o.y = ay; o.z = az; o.w = aw;
            reinterpret_cast<float4*>(V + (size_t)d * EE)[e4] = o;
        }
    }
}

// ---------------------------------------------------------------------------
// K2: combine partials into S[n,h,:] (LDS) and compute phi[n, h*64+d] = S·V[d]
// grid = N*H = 256 blocks x 256 threads
__global__ void k_phi(const float* __restrict__ P, const float* __restrict__ V,
                      float* __restrict__ phi) {
    __shared__ float S[EE];
    __shared__ float red[256];
    int n = blockIdx.x >> 3;
    int h = blockIdx.x & 7;
    for (int e = threadIdx.x; e < EE; e += 256) {
        float s = 0.f;
#pragma unroll
        for (int c = 0; c < CC; ++c)
            s += P[(((size_t)c * NN + n) * HH + h) * EE + e];
        S[e] = s;
    }
    __syncthreads();
    int d  = threadIdx.x >> 2;    // 0..63
    int ch = threadIdx.x & 3;     // 0..3 (each covers 128 e)
    const float* Vr = V + (size_t)d * EE + ch * 128;
    const float* Sr = S + ch * 128;
    float acc = 0.f;
#pragma unroll 4
    for (int e = 0; e < 128; ++e) acc += Sr[e] * Vr[e];
    red[threadIdx.x] = acc;
    __syncthreads();
    if (threadIdx.x < DD) {
        int dd = threadIdx.x;
        float r = red[dd * 4] + red[dd * 4 + 1] + red[dd * 4 + 2] + red[dd * 4 + 3];
        phi[(size_t)n * EE + h * DD + dd] = r;
    }
}

// ---------------------------------------------------------------------------
// Generic skinny GEMM: out[n][f] = act( A[n][:K] . W[f][:K] (+ bias) (+ res) )
// One wave computes NG consecutive n for FPW consecutive f. Lanes split K.
// All global loads are coalesced 1KB float4 transactions; reduce = 6x shfl_xor.
// MODE: 0 = plain, 1 = relu(s + bias), 2 = s + bias + res
template<int K, int F, int NG, int FPW, int MODE>
__global__ __launch_bounds__(256) void k_gemm(const float* __restrict__ A,
                                              const float* __restrict__ W,
                                              const float* __restrict__ bias,
                                              const float* __restrict__ res,
                                              float* __restrict__ out) {
    constexpr int V4 = K / 256;              // float4 chunks per lane
    int wid  = (blockIdx.x * 256 + threadIdx.x) >> 6;
    int lane = threadIdx.x & 63;
    constexpr int NGROUPS = NN / NG;
    int ng = wid % NGROUPS;
    int fc = wid / NGROUPS;
    int n0 = ng * NG;
    int f0 = fc * FPW;

    float4 a4[NG][V4];
#pragma unroll
    for (int g = 0; g < NG; ++g)
#pragma unroll
        for (int k = 0; k < V4; ++k)
            a4[g][k] = reinterpret_cast<const float4*>(
                A + (size_t)(n0 + g) * K)[k * 64 + lane];

#pragma unroll
    for (int fi = 0; fi < FPW; ++fi) {
        int f = f0 + fi;
        float4 w4[V4];
#pragma unroll
        for (int k = 0; k < V4; ++k)
            w4[k] = reinterpret_cast<const float4*>(
                W + (size_t)f * K)[k * 64 + lane];
        float acc[NG];
#pragma unroll
        for (int g = 0; g < NG; ++g) {
            float s = 0.f;
#pragma unroll
            for (int k = 0; k < V4; ++k) {
                s += a4[g][k].x * w4[k].x + a4[g][k].y * w4[k].y
                   + a4[g][k].z * w4[k].z + a4[g][k].w * w4[k].w;
            }
#pragma unroll
            for (int m = 32; m > 0; m >>= 1) s += __shfl_xor(s, m);
            acc[g] = s;
        }
        if (lane == 0) {
            float b = (MODE == 0) ? 0.f : bias[f];
#pragma unroll
            for (int g = 0; g < NG; ++g) {
                float v = acc[g] + b;
                if (MODE == 1) v = fmaxf(v, 0.f);
                if (MODE == 2) v += res[(size_t)(n0 + g) * F + f];
                out[(size_t)(n0 + g) * F + f] = v;
            }
        }
    }
}

// ---------------------------------------------------------------------------
// K6: LayerNorm rows of x -> out.  32 blocks x 256 threads (2 elems/thread)
__global__ void k_ln(const float* __restrict__ x, const float* __restrict__ gamma,
                     const float* __restrict__ beta, float* __restrict__ out) {
    __shared__ float wred[4];
    int n = blockIdx.x;
    int tid = threadIdx.x;
    float a = x[(size_t)n * EE + tid];
    float b = x[(size_t)n * EE + 256 + tid];
    float s = a + b;
#pragma unroll
    for (int off = 32; off > 0; off >>= 1) s += __shfl_down(s, off);
    int wid = tid >> 6;
    if ((tid & 63) == 0) wred[wid] = s;
    __syncthreads();
    if (tid == 0) wred[0] = (wred[0] + wred[1] + wred[2] + wred[3]) * (1.0f / EE);
    __syncthreads();
    float mu = wred[0];
    float da = a - mu, db = b - mu;
    float q = da * da + db * db;
#pragma unroll
    for (int off = 32; off > 0; off >>= 1) q += __shfl_down(q, off);
    __syncthreads();
    if ((tid & 63) == 0) wred[wid] = q;
    __syncthreads();
    if (tid == 0) wred[0] = (wred[0] + wred[1] + wred[2] + wred[3]) * (1.0f / EE);
    __syncthreads();
    float var = wred[0];
    float rstd = rsqrtf(var + 1e-5f);
    out[(size_t)n * EE + tid]       = da * rstd * gamma[tid] + beta[tid];
    out[(size_t)n * EE + 256 + tid] = db * rstd * gamma[tid + 256] + beta[tid + 256];
}

// ---------------------------------------------------------------------------
extern "C" void kernel_launch(void* const* d_in, const int* in_sizes, int n_in,
                              void* d_out, int out_size, void* d_ws, size_t ws_size,
                              hipStream_t stream) {
    const float* Cp    = (const float*)d_in[0];
    const float* W1    = (const float*)d_in[1];
    // d_in[2] = W2: unused — softmax over a size-1 axis is identically 1.
    const float* W3    = (const float*)d_in[3];
    const float* Wf1   = (const float*)d_in[4];
    const float* bf1   = (const float*)d_in[5];
    const float* Wf2   = (const float*)d_in[6];
    const float* bf2   = (const float*)d_in[7];
    const float* gamma = (const float*)d_in[8];
    const float* beta  = (const float*)d_in[9];
    float* out = (float*)d_out;

    float* ws  = (float*)d_ws;
    float* P   = ws;                              // 8*32*8*512 = 1,048,576 floats
    float* V   = P + (size_t)CC * NN * HH * EE;   // 64*512
    float* phi = V + (size_t)DD * EE;             // 32*512
    float* w3  = phi + (size_t)NN * EE;           // 32*512
    float* h1  = w3 + (size_t)NN * EE;            // 32*2048
    float* x   = h1 + (size_t)NN * FF;            // 32*512

    // K1: rowsum partials + W1 colsums (independent work, one launch)
    k_prep<<<2048 + 32, 128, 0, stream>>>(Cp, W1, P, V);
    // K2: phi
    k_phi<<<NN * HH, 256, 0, stream>>>(P, V, phi);
    // K3: w3 = phi @ W3^T            waves = (512/2)*(32/8) = 1024 -> 256 blocks
    k_gemm<EE, EE, 8, 2, 0><<<256, 256, 0, stream>>>(phi, W3, nullptr, nullptr, w3);
    // K4: h1 = relu(w3 @ Wf1^T + bf1) waves = (2048/2)*4 = 4096 -> 1024 blocks
    k_gemm<EE, FF, 8, 2, 1><<<1024, 256, 0, stream>>>(w3, Wf1, bf1, nullptr, h1);
    // K5: x = h1 @ Wf2^T + bf2 + w3   waves = (512/1)*(32/4) = 4096 -> 1024 blocks
    k_gemm<FF, EE, 4, 1, 2><<<1024, 256, 0, stream>>>(h1, Wf2, bf2, w3, x);
    // K6: LayerNorm
    k_ln<<<NN, 256, 0, stream>>>(x, gamma, beta, out);
}